// Round 1
// baseline (1897.297 us; speedup 1.0000x reference)
//
#include <hip/hip_runtime.h>
#include <stdint.h>

#define T_LEN 2048
#define H_DIM 4096
#define NHEAD 32
#define HDIM 128
#define FFD 11008

typedef __attribute__((ext_vector_type(8))) _Float16 f16x8;
typedef __attribute__((ext_vector_type(4))) float f32x4;

__device__ __forceinline__ float h2f(unsigned short u) {
  union { unsigned short u; _Float16 h; } v; v.u = u; return (float)v.h;
}
__device__ __forceinline__ unsigned short f2h(float f) {
  union { _Float16 h; unsigned short u; } v; v.h = (_Float16)f; return v.u;
}

// ---------------- weight transpose + fp32->fp16 convert: in[K][N] -> out[N][K]
__global__ __launch_bounds__(256) void transpose_cvt(const float* __restrict__ in,
                                                     unsigned short* __restrict__ out,
                                                     int K, int N) {
  __shared__ float tile[64][65];
  const int tid = threadIdx.x;
  const long n0 = (long)blockIdx.x * 64;
  const long k0 = (long)blockIdx.y * 64;
  const int rr = tid >> 4;
  const int cc = (tid & 15) * 4;
#pragma unroll
  for (int i = 0; i < 4; ++i) {
    int r = rr + i * 16;
    float4 v = *(const float4*)(in + (k0 + r) * N + n0 + cc);
    tile[r][cc + 0] = v.x; tile[r][cc + 1] = v.y;
    tile[r][cc + 2] = v.z; tile[r][cc + 3] = v.w;
  }
  __syncthreads();
#pragma unroll
  for (int i = 0; i < 4; ++i) {
    int n = rr + i * 16;
    union { ushort4 u4; unsigned short s[4]; } p;
    p.s[0] = f2h(tile[cc + 0][n]);
    p.s[1] = f2h(tile[cc + 1][n]);
    p.s[2] = f2h(tile[cc + 2][n]);
    p.s[3] = f2h(tile[cc + 3][n]);
    *(ushort4*)(out + (n0 + n) * K + k0 + cc) = p.u4;
  }
}

__global__ void concat3(const float* __restrict__ a, const float* __restrict__ b,
                        const float* __restrict__ c, float* __restrict__ out) {
  int i = blockIdx.x * 256 + threadIdx.x;
  out[i] = (i < 4096) ? a[i] : (i < 8192) ? b[i - 4096] : c[i - 8192];
}

// ---------------- RMSNorm fp32 -> fp16
__global__ __launch_bounds__(256) void rmsnorm_k(const float* __restrict__ x,
                                                 const float* __restrict__ scale,
                                                 unsigned short* __restrict__ out) {
  const int row = blockIdx.x;
  const int tid = threadIdx.x;
  const float* xr = x + (long)row * H_DIM;
  float4 v[4];
  float ss = 0.f;
#pragma unroll
  for (int i = 0; i < 4; ++i) {
    v[i] = *(const float4*)(xr + (tid + (i << 8)) * 4);
    ss += v[i].x * v[i].x + v[i].y * v[i].y + v[i].z * v[i].z + v[i].w * v[i].w;
  }
#pragma unroll
  for (int off = 32; off; off >>= 1) ss += __shfl_xor(ss, off, 64);
  __shared__ float sred[4];
  if ((tid & 63) == 0) sred[tid >> 6] = ss;
  __syncthreads();
  float total = sred[0] + sred[1] + sred[2] + sred[3];
  const float rms = rsqrtf(total * (1.0f / H_DIM) + 1e-6f);
  unsigned short* orow = out + (long)row * H_DIM;
#pragma unroll
  for (int i = 0; i < 4; ++i) {
    const int c = (tid + (i << 8)) * 4;
    union { ushort4 u4; unsigned short s[4]; } p;
    p.s[0] = f2h(v[i].x * rms * scale[c + 0]);
    p.s[1] = f2h(v[i].y * rms * scale[c + 1]);
    p.s[2] = f2h(v[i].z * rms * scale[c + 2]);
    p.s[3] = f2h(v[i].w * rms * scale[c + 3]);
    *(ushort4*)(orow + c) = p.u4;
  }
}

// ---------------- GEMM: C[M][N] = A[M][K](f16) * B[N][K](f16)^T (+bias)(+resid)
// 128x128 tile, BK=64, 4 waves of 64x64, global_load_lds staging, XOR-swizzled LDS.
__global__ __launch_bounds__(256, 2) void gemm128(
    const unsigned short* __restrict__ A, const unsigned short* __restrict__ B,
    const float* __restrict__ bias, const float* __restrict__ resid,
    float* __restrict__ outF, unsigned short* __restrict__ outH,
    int M, int N, int K) {
  __shared__ __align__(16) unsigned short As[128 * 64];
  __shared__ __align__(16) unsigned short Bs[128 * 64];
  const int tid = threadIdx.x;
  const int wave = tid >> 6, lane = tid & 63;
  const int m16 = lane & 15, quad = lane >> 4;
  const int wm = (wave & 1) << 6, wn = (wave >> 1) << 6;
  const long rowBase = (long)blockIdx.x * 128;
  const long colBase = (long)blockIdx.y * 128;

  f32x4 acc[4][4] = {};
  const int nK = K >> 6;
  for (int kt = 0; kt < nK; ++kt) {
    __syncthreads();
    const long k0 = (long)kt << 6;
#pragma unroll
    for (int i = 0; i < 4; ++i) {
      const int c = wave * 4 + i;
      const int s = c * 64 + lane;
      const int r = s >> 3;
      const int gk = (s & 7) ^ (r & 7);  // XOR swizzle: LDS slot (r, s&7) holds global granule gk
      const unsigned short* gA = A + (rowBase + r) * K + k0 + gk * 8;
      const unsigned short* gB = B + (colBase + r) * K + k0 + gk * 8;
      __builtin_amdgcn_global_load_lds((__attribute__((address_space(1))) void*)gA,
                                       (__attribute__((address_space(3))) void*)(As + c * 512), 16, 0, 0);
      __builtin_amdgcn_global_load_lds((__attribute__((address_space(1))) void*)gB,
                                       (__attribute__((address_space(3))) void*)(Bs + c * 512), 16, 0, 0);
    }
    __syncthreads();
#pragma unroll
    for (int ks = 0; ks < 2; ++ks) {
      f16x8 af[4], bf[4];
#pragma unroll
      for (int im = 0; im < 4; ++im) {
        int r = wm + im * 16 + m16;
        int gpos = ((ks << 2) + quad) ^ (r & 7);
        af[im] = *(const f16x8*)(As + r * 64 + gpos * 8);
      }
#pragma unroll
      for (int in = 0; in < 4; ++in) {
        int r = wn + in * 16 + m16;
        int gpos = ((ks << 2) + quad) ^ (r & 7);
        bf[in] = *(const f16x8*)(Bs + r * 64 + gpos * 8);
      }
#pragma unroll
      for (int im = 0; im < 4; ++im)
#pragma unroll
        for (int in = 0; in < 4; ++in)
          acc[im][in] = __builtin_amdgcn_mfma_f32_16x16x32_f16(af[im], bf[in], acc[im][in], 0, 0, 0);
    }
  }
#pragma unroll
  for (int im = 0; im < 4; ++im) {
#pragma unroll
    for (int in = 0; in < 4; ++in) {
      const long col = colBase + wn + in * 16 + m16;
      float bv = bias ? bias[col] : 0.0f;
#pragma unroll
      for (int r = 0; r < 4; ++r) {
        const long row = rowBase + wm + im * 16 + quad * 4 + r;
        float x = acc[im][in][r] + bv;
        if (resid) x += resid[row * N + col];
        if (outF) outF[row * N + col] = x;
        else outH[row * N + col] = f2h(x);
      }
    }
  }
}

// ---------------- RoPE on q,k (qkv fp16 [T][3H]) -> qh,kh [NH][T][HD]; q pre-scaled by HD^-0.5
__global__ __launch_bounds__(256) void rope_qk(const unsigned short* __restrict__ qkv,
                                               const int* __restrict__ pos,
                                               unsigned short* __restrict__ qh,
                                               unsigned short* __restrict__ kh) {
  const int h = blockIdx.x;
  const int t = blockIdx.y * 4 + (threadIdx.x >> 6);
  const int j = threadIdx.x & 63;
  const float p = (float)pos[t];
  // inv_freq = 10000^(-(2j)/128) = exp(-j/64 * ln(1e4))
  const float inv = expf(-(float)j * (9.210340371976184f / 64.0f));
  float sv, cv;
  sincosf(p * inv, &sv, &cv);
  const long base = (long)t * 12288 + h * 128;
  float q1 = h2f(qkv[base + j]), q2 = h2f(qkv[base + 64 + j]);
  float k1 = h2f(qkv[base + 4096 + j]), k2 = h2f(qkv[base + 4096 + 64 + j]);
  const float sc = 0.08838834764831845f;  // HD^-0.5
  const long ob = ((long)h * T_LEN + t) * 128;
  qh[ob + j]      = f2h((q1 * cv - q2 * sv) * sc);
  qh[ob + 64 + j] = f2h((q2 * cv + q1 * sv) * sc);
  kh[ob + j]      = f2h(k1 * cv - k2 * sv);
  kh[ob + 64 + j] = f2h(k2 * cv + k1 * sv);
}

// ---------------- V transpose: qkv v-part [T][NH*HD] -> vt [NH][HD][T] (fp16 bits copy)
__global__ __launch_bounds__(256) void v_trans(const unsigned short* __restrict__ qkv,
                                               unsigned short* __restrict__ vt) {
  __shared__ __align__(16) unsigned short tile[64 * 136];
  const int t0 = blockIdx.x * 64;
  const int h = blockIdx.y;
  const int tid = threadIdx.x;
#pragma unroll
  for (int i = 0; i < 4; ++i) {
    int idx = tid + (i << 8);                 // 0..1023: 64 rows x 16 granules
    int tl = idx >> 4, c8 = (idx & 15) * 8;
    *(int4*)(tile + tl * 136 + c8) =
        *(const int4*)(qkv + (long)(t0 + tl) * 12288 + 8192 + h * 128 + c8);
  }
  __syncthreads();
#pragma unroll
  for (int i = 0; i < 4; ++i) {
    int idx = tid + (i << 8);                 // 0..1023: 128 rows x 8 granules
    int d = idx >> 3, t8 = (idx & 7) * 8;
    union { int4 v; unsigned short s[8]; } p;
#pragma unroll
    for (int e = 0; e < 8; ++e) p.s[e] = tile[(t8 + e) * 136 + d];
    *(int4*)(vt + ((long)h * 128 + d) * T_LEN + t0 + t8) = p.v;
  }
}

// ---------------- causal flash attention, 128 q-rows/block, 64-key tiles
__global__ __launch_bounds__(256, 2) void attn_flash(
    const unsigned short* __restrict__ Qh, const unsigned short* __restrict__ Kh,
    const unsigned short* __restrict__ Vt, unsigned short* __restrict__ O) {
  const int h = blockIdx.y;
  const int qb = gridDim.x - 1 - blockIdx.x;  // big blocks first
  const int tid = threadIdx.x, wave = tid >> 6, lane = tid & 63;
  const int m16 = lane & 15, quad = lane >> 4;
  __shared__ __align__(16) unsigned short Kt[64 * 136];
  __shared__ __align__(16) unsigned short Vs[128 * 72];
  __shared__ __align__(16) unsigned short Pb[128 * 72];

  f16x8 qf[2][4];
  {
    const long qbase = ((long)h * T_LEN + qb * 128 + wave * 32) * 128;
#pragma unroll
    for (int im = 0; im < 2; ++im)
#pragma unroll
      for (int kd = 0; kd < 4; ++kd)
        qf[im][kd] = *(const f16x8*)(Qh + qbase + (im * 16 + m16) * 128 + kd * 32 + quad * 8);
  }
  f32x4 o[2][8] = {};
  float m_s[2][4], l_s[2][4];
#pragma unroll
  for (int im = 0; im < 2; ++im)
#pragma unroll
    for (int r = 0; r < 4; ++r) { m_s[im][r] = -1e30f; l_s[im][r] = 0.f; }

  const int nKT = 2 * qb + 2;
  for (int kt = 0; kt < nKT; ++kt) {
    __syncthreads();
#pragma unroll
    for (int i = 0; i < 4; ++i) {
      int g = tid + (i << 8);
      int r = g >> 4, c8 = (g & 15) * 8;
      *(int4*)(Kt + r * 136 + c8) =
          *(const int4*)(Kh + ((long)h * T_LEN + kt * 64 + r) * 128 + c8);
    }
#pragma unroll
    for (int i = 0; i < 4; ++i) {
      int g = tid + (i << 8);
      int r = g >> 3, c8 = (g & 7) * 8;
      *(int4*)(Vs + r * 72 + c8) =
          *(const int4*)(Vt + ((long)h * 128 + r) * T_LEN + kt * 64 + c8);
    }
    __syncthreads();

    f32x4 s[2][4] = {};
#pragma unroll
    for (int in = 0; in < 4; ++in)
#pragma unroll
      for (int kd = 0; kd < 4; ++kd) {
        f16x8 kf = *(const f16x8*)(Kt + (in * 16 + m16) * 136 + kd * 32 + quad * 8);
        s[0][in] = __builtin_amdgcn_mfma_f32_16x16x32_f16(qf[0][kd], kf, s[0][in], 0, 0, 0);
        s[1][in] = __builtin_amdgcn_mfma_f32_16x16x32_f16(qf[1][kd], kf, s[1][in], 0, 0, 0);
      }
    if (kt >= 2 * qb) {  // diagonal tiles: causal mask
#pragma unroll
      for (int im = 0; im < 2; ++im)
#pragma unroll
        for (int in = 0; in < 4; ++in)
#pragma unroll
          for (int r = 0; r < 4; ++r) {
            int rowg = qb * 128 + wave * 32 + im * 16 + quad * 4 + r;
            int colg = kt * 64 + in * 16 + m16;
            if (colg > rowg) s[im][in][r] = -1e30f;
          }
    }
#pragma unroll
    for (int im = 0; im < 2; ++im)
#pragma unroll
      for (int r = 0; r < 4; ++r) {
        float mx = fmaxf(fmaxf(s[im][0][r], s[im][1][r]), fmaxf(s[im][2][r], s[im][3][r]));
#pragma unroll
        for (int off = 1; off < 16; off <<= 1) mx = fmaxf(mx, __shfl_xor(mx, off, 64));
        float mn = fmaxf(m_s[im][r], mx);
        float al = __expf(m_s[im][r] - mn);
        m_s[im][r] = mn;
        float rs = 0.f;
#pragma unroll
        for (int in = 0; in < 4; ++in) {
          float p = __expf(s[im][in][r] - mn);
          s[im][in][r] = p;
          rs += p;
        }
#pragma unroll
        for (int off = 1; off < 16; off <<= 1) rs += __shfl_xor(rs, off, 64);
        l_s[im][r] = l_s[im][r] * al + rs;
#pragma unroll
        for (int dt = 0; dt < 8; ++dt) o[im][dt][r] *= al;
        const int prow = wave * 32 + im * 16 + quad * 4 + r;
#pragma unroll
        for (int in = 0; in < 4; ++in)
          Pb[prow * 72 + in * 16 + m16] = f2h(s[im][in][r]);
      }
    asm volatile("s_waitcnt lgkmcnt(0)" ::: "memory");  // P writes visible to own wave reads
#pragma unroll
    for (int kb = 0; kb < 2; ++kb) {
      f16x8 pf0 = *(const f16x8*)(Pb + (wave * 32 + m16) * 72 + kb * 32 + quad * 8);
      f16x8 pf1 = *(const f16x8*)(Pb + (wave * 32 + 16 + m16) * 72 + kb * 32 + quad * 8);
#pragma unroll
      for (int dt = 0; dt < 8; ++dt) {
        f16x8 vf = *(const f16x8*)(Vs + (dt * 16 + m16) * 72 + kb * 32 + quad * 8);
        o[0][dt] = __builtin_amdgcn_mfma_f32_16x16x32_f16(pf0, vf, o[0][dt], 0, 0, 0);
        o[1][dt] = __builtin_amdgcn_mfma_f32_16x16x32_f16(pf1, vf, o[1][dt], 0, 0, 0);
      }
    }
  }
#pragma unroll
  for (int im = 0; im < 2; ++im)
#pragma unroll
    for (int r = 0; r < 4; ++r) {
      float inv = 1.0f / l_s[im][r];
      long tg = (long)qb * 128 + wave * 32 + im * 16 + quad * 4 + r;
#pragma unroll
      for (int dt = 0; dt < 8; ++dt)
        O[tg * H_DIM + h * 128 + dt * 16 + m16] = f2h(o[im][dt][r] * inv);
    }
}

// ---------------- g = a1 * silu(a2); a12 fp16 [T][2*FF] -> g fp16 [T][FF]
__global__ __launch_bounds__(256) void silu_mul(const unsigned short* __restrict__ a12,
                                                unsigned short* __restrict__ g) {
  const int row = blockIdx.x;
  const long b1 = (long)row * (2 * FFD);
  const long bo = (long)row * FFD;
  for (int gr = threadIdx.x; gr < FFD / 8; gr += 256) {
    union { int4 v; unsigned short s[8]; } x, y, o;
    x.v = *(const int4*)(a12 + b1 + gr * 8);
    y.v = *(const int4*)(a12 + b1 + FFD + gr * 8);
#pragma unroll
    for (int e = 0; e < 8; ++e) {
      float a = h2f(x.s[e]), b = h2f(y.s[e]);
      o.s[e] = f2h(a * (b / (1.0f + __expf(-b))));
    }
    *(int4*)(g + bo + gr * 8) = o.v;
  }
}

extern "C" void kernel_launch(void* const* d_in, const int* in_sizes, int n_in,
                              void* d_out, int out_size, void* d_ws, size_t ws_size,
                              hipStream_t stream) {
  (void)in_sizes; (void)n_in; (void)out_size; (void)ws_size;
  const int* positions = (const int*)d_in[0];
  const float* hidden = (const float*)d_in[1];
  const float* ln1 = (const float*)d_in[2];
  const float* wq = (const float*)d_in[3];
  const float* bq = (const float*)d_in[4];
  const float* wk = (const float*)d_in[5];
  const float* bk = (const float*)d_in[6];
  const float* wv = (const float*)d_in[7];
  const float* bv = (const float*)d_in[8];
  const float* wo = (const float*)d_in[9];
  const float* ln2 = (const float*)d_in[10];
  const float* w1 = (const float*)d_in[11];
  const float* w2 = (const float*)d_in[12];
  const float* wc = (const float*)d_in[13];
  float* out = (float*)d_out;

  char* ws = (char*)d_ws;
  size_t off = 0;
  auto alloc = [&](size_t bytes) {
    char* p = ws + off;
    off += (bytes + 255) & ~(size_t)255;
    return p;
  };
  unsigned short* wqkvT = (unsigned short*)alloc((size_t)3 * H_DIM * H_DIM * 2);
  unsigned short* woT   = (unsigned short*)alloc((size_t)H_DIM * H_DIM * 2);
  unsigned short* w12T  = (unsigned short*)alloc((size_t)2 * FFD * H_DIM * 2);
  unsigned short* wcT   = (unsigned short*)alloc((size_t)H_DIM * FFD * 2);
  float* biasq          = (float*)alloc(12288 * 4);
  unsigned short* xb    = (unsigned short*)alloc((size_t)T_LEN * H_DIM * 2);
  unsigned short* qkv   = (unsigned short*)alloc((size_t)T_LEN * 12288 * 2);
  unsigned short* qh    = (unsigned short*)alloc((size_t)T_LEN * H_DIM * 2);
  unsigned short* kh    = (unsigned short*)alloc((size_t)T_LEN * H_DIM * 2);
  unsigned short* vt    = (unsigned short*)alloc((size_t)T_LEN * H_DIM * 2);
  unsigned short* attnb = (unsigned short*)alloc((size_t)T_LEN * H_DIM * 2);
  float* hbuf           = (float*)alloc((size_t)T_LEN * H_DIM * 4);
  unsigned short* yb    = (unsigned short*)alloc((size_t)T_LEN * H_DIM * 2);
  unsigned short* a12   = (unsigned short*)alloc((size_t)T_LEN * 2 * FFD * 2);
  unsigned short* gb    = (unsigned short*)alloc((size_t)T_LEN * FFD * 2);

  concat3<<<48, 256, 0, stream>>>(bq, bk, bv, biasq);
  transpose_cvt<<<dim3(64, 64), 256, 0, stream>>>(wq, wqkvT, H_DIM, H_DIM);
  transpose_cvt<<<dim3(64, 64), 256, 0, stream>>>(wk, wqkvT + (size_t)H_DIM * H_DIM, H_DIM, H_DIM);
  transpose_cvt<<<dim3(64, 64), 256, 0, stream>>>(wv, wqkvT + (size_t)2 * H_DIM * H_DIM, H_DIM, H_DIM);
  transpose_cvt<<<dim3(64, 64), 256, 0, stream>>>(wo, woT, H_DIM, H_DIM);
  transpose_cvt<<<dim3(172, 64), 256, 0, stream>>>(w1, w12T, H_DIM, FFD);
  transpose_cvt<<<dim3(172, 64), 256, 0, stream>>>(w2, w12T + (size_t)FFD * H_DIM, H_DIM, FFD);
  transpose_cvt<<<dim3(64, 172), 256, 0, stream>>>(wc, wcT, FFD, H_DIM);

  rmsnorm_k<<<T_LEN, 256, 0, stream>>>(hidden, ln1, xb);
  gemm128<<<dim3(16, 96), 256, 0, stream>>>(xb, wqkvT, biasq, nullptr, nullptr, qkv,
                                            T_LEN, 3 * H_DIM, H_DIM);
  rope_qk<<<dim3(NHEAD, T_LEN / 4), 256, 0, stream>>>(qkv, positions, qh, kh);
  v_trans<<<dim3(T_LEN / 64, NHEAD), 256, 0, stream>>>(qkv, vt);
  attn_flash<<<dim3(T_LEN / 128, NHEAD), 256, 0, stream>>>(qh, kh, vt, attnb);
  gemm128<<<dim3(16, 32), 256, 0, stream>>>(attnb, woT, nullptr, hidden, hbuf, nullptr,
                                            T_LEN, H_DIM, H_DIM);
  rmsnorm_k<<<T_LEN, 256, 0, stream>>>(hbuf, ln2, yb);
  gemm128<<<dim3(16, 172), 256, 0, stream>>>(yb, w12T, nullptr, nullptr, nullptr, a12,
                                             T_LEN, 2 * FFD, H_DIM);
  silu_mul<<<T_LEN, 256, 0, stream>>>(a12, gb);
  gemm128<<<dim3(16, 32), 256, 0, stream>>>(gb, wcT, nullptr, hbuf, out, nullptr,
                                            T_LEN, H_DIM, FFD);
}